// Round 13
// baseline (21736.401 us; speedup 1.0000x reference)
//
#include <hip/hip_runtime.h>
#include <math.h>

// Problem constants (fixed by setup_inputs)
#define BB  64      // batch
#define TT  512     // seq len
#define HH  512     // hidden
#define RR  1024    // decode rows = B*S
#define HOR 64      // horizon
#define WST 520     // encoder LDS weight row stride (floats)

// encoder geometry
#define ENW 128     // encoder WGs (each owns 4 hcols)
#define ENT 1024    // encoder threads/WG

typedef unsigned short ushort;
typedef __attribute__((ext_vector_type(8))) short bf16x8;     // 8 bf16 (4 VGPRs)
typedef __attribute__((ext_vector_type(8))) unsigned short ushort8;
typedef __attribute__((ext_vector_type(4))) float f32x4;

// Persistent state in device globals (re-initialized every launch)
__device__ float g_h0[2][BB][HH];
__device__ float g_h1[2][BB][HH];
__device__ float g_c0[BB][HH];
__device__ float g_c1[BB][HH];
__device__ float g_C0[RR][HH];
__device__ float g_C1[RR][HH];
__device__ float g_u[2][RR];       // u double-buffer: g_u[d&1] feeds step d
// split-bf16 decoder state (hi + lo residual; GEMM A operands)
__device__ ushort H0h[2][RR][HH], H0l[2][RR][HH];
__device__ ushort H1h[2][RR][HH], H1l[2][RR][HH];
// split-bf16 weights (prep kernel, once per launch)
__device__ ushort Whh0h[4 * HH][HH], Whh0l[4 * HH][HH];
__device__ ushort Wih1h[4 * HH][HH], Wih1l[4 * HH][HH];
__device__ ushort Whh1h[4 * HH][HH], Whh1l[4 * HH][HH];

__device__ __forceinline__ float sigf(float v) { return 1.0f / (1.0f + expf(-v)); }

__device__ __forceinline__ float cellupd(float iv, float fv, float gv, float ov, float& c) {
  c = sigf(fv) * c + sigf(iv) * tanhf(gv);
  return sigf(ov) * tanhf(c);
}

// bf16 RNE helpers
__device__ __forceinline__ ushort f2bf(float x) {
  unsigned u = __float_as_uint(x);
  unsigned r = u + 0x7FFFu + ((u >> 16) & 1u);
  return (ushort)(r >> 16);
}
__device__ __forceinline__ float bf2f(ushort h) {
  return __uint_as_float(((unsigned)h) << 16);
}

// ---- Split pipelined barriers (encoder) ----
// Batch halves A/B have INDEPENDENT barrier slot arrays. Arrival: one wbl2
// fence + relaxed store to own cacheline. Wait: 128 lanes poll the 128 slots
// directly (no master/flag round trip), then one inv fence. The wait for
// half X is issued a full half-phase after its arrivals -> latency hidden
// behind the other half's compute. SAFETY (R2/R4 hangs): ~104KB LDS ->
// 1 WG/CU; 128 WGs vs 256 CUs = 2x co-residency slack. Keep it so.
__device__ __forceinline__ void bar_arrive(unsigned* slots, unsigned p) {
  __syncthreads();  // all waves' stores retired (vmcnt drained at barrier)
  if (threadIdx.x == 0) {
    __threadfence();  // wbl2: publish this WG's writes
    __hip_atomic_store(slots + blockIdx.x * 32, p, __ATOMIC_RELAXED,
                       __HIP_MEMORY_SCOPE_AGENT);
  }
}
__device__ __forceinline__ void bar_wait(unsigned* slots, unsigned p) {
  if (threadIdx.x < ENW) {
    while (__hip_atomic_load(slots + threadIdx.x * 32, __ATOMIC_RELAXED,
                             __HIP_MEMORY_SCOPE_AGENT) < p)
      __builtin_amdgcn_s_sleep(1);
  }
  __syncthreads();
  if (threadIdx.x == 0) __threadfence();  // inv: fresh reads of peers' state
  __syncthreads();
}

// Reduce 32 values across a 32-lane half-wave (HW-verified R3-R12).
__device__ __forceinline__ float bfly32(float (&v)[32], const int ks) {
  float a16[16];
#pragma unroll
  for (int j = 0; j < 16; ++j) {
    const float lo = v[j], hi = v[j + 16];
    const float send = (ks & 16) ? lo : hi;
    const float recv = __shfl_xor(send, 16);
    a16[j] = ((ks & 16) ? hi : lo) + recv;
  }
  float a8[8];
#pragma unroll
  for (int j = 0; j < 8; ++j) {
    const float lo = a16[j], hi = a16[j + 8];
    const float send = (ks & 8) ? lo : hi;
    const float recv = __shfl_xor(send, 8);
    a8[j] = ((ks & 8) ? hi : lo) + recv;
  }
  float a4[4];
#pragma unroll
  for (int j = 0; j < 4; ++j) {
    const float lo = a8[j], hi = a8[j + 4];
    const float send = (ks & 4) ? lo : hi;
    const float recv = __shfl_xor(send, 4);
    a4[j] = ((ks & 4) ? hi : lo) + recv;
  }
  float a2[2];
#pragma unroll
  for (int j = 0; j < 2; ++j) {
    const float lo = a4[j], hi = a4[j + 2];
    const float send = (ks & 2) ? lo : hi;
    const float recv = __shfl_xor(send, 2);
    a2[j] = ((ks & 2) ? hi : lo) + recv;
  }
  const float lo = a2[0], hi = a2[1];
  const float send = (ks & 1) ? lo : hi;
  const float recv = __shfl_xor(send, 1);
  return ((ks & 1) ? hi : lo) + recv;
}

// ======================= PREP: split weights to bf16 hi/lo =======================
__global__ __launch_bounds__(512) void prep_split(
    const float* __restrict__ whh0, const float* __restrict__ wih1,
    const float* __restrict__ whh1) {
  const int i = blockIdx.x * 512 + threadIdx.x;  // grid 2048 -> 1M elements
  float a = whh0[i];
  ushort h = f2bf(a);
  (&Whh0h[0][0])[i] = h;
  (&Whh0l[0][0])[i] = f2bf(a - bf2f(h));
  a = wih1[i];
  h = f2bf(a);
  (&Wih1h[0][0])[i] = h;
  (&Wih1l[0][0])[i] = f2bf(a - bf2f(h));
  a = whh1[i];
  h = f2bf(a);
  (&Whh1h[0][0])[i] = h;
  (&Whh1l[0][0])[i] = f2bf(a - bf2f(h));
}

// ======================= ENCODER (persistent, batch-split pipeline) ============
// 128 WGs x 1024 thr. WG owns hcols jh0..jh0+3 (16 gate-rows/matrix).
// Batch split into halves A (rows 0-31) / B (rows 32-63) -- independent
// recurrence chains with independent barriers, interleaved so each barrier
// completes in the shadow of the other half's compute.
// Per half-phase thread tile: 4 rows x 8 gate-rows x ks64 (8 k-els).
// L0 and L1 run SEQUENTIALLY with one reused acc[32] (no spill at 64 VGPR).
__global__ __launch_bounds__(ENT, 4) void enc_kernel(
    const float* __restrict__ x, const float* __restrict__ init_input,
    const float* __restrict__ w_ih0, const float* __restrict__ w_hh0,
    const float* __restrict__ b0, const float* __restrict__ w_ih1,
    const float* __restrict__ w_hh1, const float* __restrict__ b1,
    unsigned* ws) {
  const int wg = blockIdx.x;
  const int tid = threadIdx.x;
  const int jh0 = wg * 4;
  unsigned* wsA = ws;               // 128 slots x 32 stride
  unsigned* wsB = ws + 4096;
  unsigned* wsI = ws + 8192;

  __shared__ __align__(16) float s_whh0[16 * WST];
  __shared__ __align__(16) float s_wih1[16 * WST];
  __shared__ __align__(16) float s_whh1[16 * WST];
  __shared__ __align__(16) float s_gb0[32 * 16];  // [lrow][q][gate]
  __shared__ __align__(16) float s_gb1[32 * 16];
  __shared__ float s_wih0[16], s_b0[16], s_b1[16];

  for (int i = tid; i < 16 * HH; i += ENT) {
    const int r16 = i >> 9, k = i & 511;
    const int j = (r16 >> 2) * HH + jh0 + (r16 & 3);  // gate=r16>>2, q=r16&3
    s_whh0[r16 * WST + k] = w_hh0[j * HH + k];
    s_wih1[r16 * WST + k] = w_ih1[j * HH + k];
    s_whh1[r16 * WST + k] = w_hh1[j * HH + k];
  }
  if (tid < 16) {
    const int j = (tid >> 2) * HH + jh0 + (tid & 3);
    s_wih0[tid] = w_ih0[j];
    s_b0[tid] = b0[j];
    s_b1[tid] = b1[j];
  }
  {  // zero-init encoder state
    int idx = wg * ENT + tid;
    if (idx < 2 * BB * HH) {
      (&g_h0[0][0][0])[idx] = 0.f;
      (&g_h1[0][0][0])[idx] = 0.f;
    }
    if (idx < BB * HH) {
      (&g_c0[0][0])[idx] = 0.f;
      (&g_c1[0][0])[idx] = 0.f;
    }
  }
  bar_arrive(wsI, 1);
  bar_wait(wsI, 1);

  const int gg = tid >> 9;           // gate half: rows gg*8..gg*8+7
  const int rgrp = (tid >> 6) & 7;   // 8 row-groups x 4 rows = 32 rows/half
  const int ks = tid & 63;           // K-split 64: k = ks*4 + j*256
  const int ksl = ks & 31;
  const int r16o = gg * 8 + (ksl & 7);       // output gate-row
  const int lrow = rgrp * 4 + (ksl >> 3);    // output local row (0..31)
  const int eslot = lrow * 16 + (r16o & 3) * 4 + (r16o >> 2);  // [lrow][q][gate]

#define ENC_HALF(HB, PTK)                                                      \
  {                                                                            \
    const int rb = (HB) * 32;                                                  \
    const int cur = ((PTK)-1) & 1, nxt = (PTK)&1;                              \
    const bool do0 = ((PTK) <= TT), do1 = ((PTK) >= 2);                        \
    float acc[32];                                                             \
    if (do0) { /* L0: h0 @ whh0^T */                                           \
      _Pragma("unroll") for (int v = 0; v < 32; ++v) acc[v] = 0.f;             \
      _Pragma("unroll") for (int j = 0; j < 2; ++j) {                          \
        const int k = ks * 4 + j * 256;                                        \
        float4 hv[4];                                                          \
        _Pragma("unroll") for (int r = 0; r < 4; ++r)                          \
            hv[r] = *(const float4*)&g_h0[cur][rb + rgrp * 4 + r][k];          \
        _Pragma("unroll") for (int g = 0; g < 8; ++g) {                        \
          const float4 wv = *(const float4*)&s_whh0[(gg * 8 + g) * WST + k];   \
          _Pragma("unroll") for (int r = 0; r < 4; ++r) {                      \
            acc[r * 8 + g] = fmaf(hv[r].x, wv.x, acc[r * 8 + g]);              \
            acc[r * 8 + g] = fmaf(hv[r].y, wv.y, acc[r * 8 + g]);              \
            acc[r * 8 + g] = fmaf(hv[r].z, wv.z, acc[r * 8 + g]);              \
            acc[r * 8 + g] = fmaf(hv[r].w, wv.w, acc[r * 8 + g]);              \
          }                                                                    \
        }                                                                      \
      }                                                                        \
      float rr = bfly32(acc, ksl);                                             \
      rr += __shfl_xor(rr, 32);                                                \
      if (ks < 32) {                                                           \
        rr += x[(rb + lrow) * TT + ((PTK)-1)] * s_wih0[r16o] + s_b0[r16o];     \
        s_gb0[eslot] = rr;                                                     \
      }                                                                        \
    }                                                                          \
    if (do1) { /* L1: h0 @ wih1^T + h1 @ whh1^T */                             \
      _Pragma("unroll") for (int v = 0; v < 32; ++v) acc[v] = 0.f;             \
      _Pragma("unroll") for (int j = 0; j < 2; ++j) {                          \
        const int k = ks * 4 + j * 256;                                        \
        float4 hv[4];                                                          \
        _Pragma("unroll") for (int r = 0; r < 4; ++r)                          \
            hv[r] = *(const float4*)&g_h0[cur][rb + rgrp * 4 + r][k];          \
        _Pragma("unroll") for (int g = 0; g < 8; ++g) {                        \
          const float4 wv = *(const float4*)&s_wih1[(gg * 8 + g) * WST + k];   \
          _Pragma("unroll") for (int r = 0; r < 4; ++r) {                      \
            acc[r * 8 + g] = fmaf(hv[r].x, wv.x, acc[r * 8 + g]);              \
            acc[r * 8 + g] = fmaf(hv[r].y, wv.y, acc[r * 8 + g]);              \
            acc[r * 8 + g] = fmaf(hv[r].z, wv.z, acc[r * 8 + g]);              \
            acc[r * 8 + g] = fmaf(hv[r].w, wv.w, acc[r * 8 + g]);              \
          }                                                                    \
        }                                                                      \
      }                                                                        \
      _Pragma("unroll") for (int j = 0; j < 2; ++j) {                          \
        const int k = ks * 4 + j * 256;                                        \
        float4 hv[4];                                                          \
        _Pragma("unroll") for (int r = 0; r < 4; ++r)                          \
            hv[r] = *(const float4*)&g_h1[nxt][rb + rgrp * 4 + r][k];          \
        _Pragma("unroll") for (int g = 0; g < 8; ++g) {                        \
          const float4 wv = *(const float4*)&s_whh1[(gg * 8 + g) * WST + k];   \
          _Pragma("unroll") for (int r = 0; r < 4; ++r) {                      \
            acc[r * 8 + g] = fmaf(hv[r].x, wv.x, acc[r * 8 + g]);              \
            acc[r * 8 + g] = fmaf(hv[r].y, wv.y, acc[r * 8 + g]);              \
            acc[r * 8 + g] = fmaf(hv[r].z, wv.z, acc[r * 8 + g]);              \
            acc[r * 8 + g] = fmaf(hv[r].w, wv.w, acc[r * 8 + g]);              \
          }                                                                    \
        }                                                                      \
      }                                                                        \
      float rr = bfly32(acc, ksl);                                             \
      rr += __shfl_xor(rr, 32);                                                \
      if (ks < 32) s_gb1[eslot] = rr + s_b1[r16o];                             \
    }                                                                          \
    __syncthreads();                                                           \
    if (do0 && tid < 128) { /* cell0 -> h0^{tk} */                             \
      const int lr = tid >> 2, q = tid & 3, b = rb + lr, jh = jh0 + q;         \
      const float4 gv = *(const float4*)&s_gb0[lr * 16 + q * 4];               \
      float c = g_c0[b][jh];                                                   \
      g_h0[nxt][b][jh] = cellupd(gv.x, gv.y, gv.z, gv.w, c);                   \
      g_c0[b][jh] = c;                                                         \
    }                                                                          \
    if (do1 && tid >= 128 && tid < 256) { /* cell1 -> h1^{tk-1} */             \
      const int t2 = tid - 128, lr = t2 >> 2, q = t2 & 3;                      \
      const int b = rb + lr, jh = jh0 + q;                                     \
      const float4 gv = *(const float4*)&s_gb1[lr * 16 + q * 4];               \
      float c = g_c1[b][jh];                                                   \
      g_h1[cur][b][jh] = cellupd(gv.x, gv.y, gv.z, gv.w, c);                   \
      g_c1[b][jh] = c;                                                         \
    }                                                                          \
  }

  unsigned pA = 0, pB = 0;
  for (int tk = 1; tk <= TT + 1; ++tk) {
    bar_wait(wsA, pA);      // nearly-free: had a half-phase to complete
    ENC_HALF(0, tk)
    bar_arrive(wsA, ++pA);
    bar_wait(wsB, pB);
    ENC_HALF(1, tk)
    bar_arrive(wsB, ++pB);
  }
  bar_wait(wsA, pA);
  bar_wait(wsB, pB);

  // ---- expand final states over n_samples: row r = b*16+s; emit bf16 hi/lo ----
  {
    int gt = wg * ENT + tid;         // 0..131071 == RR*HH/4 float4 slots
    int r = gt >> 7, k4 = gt & 127;
    int b = r >> 4;
    const float4 h0v = ((const float4*)&g_h0[0][b][0])[k4];
    const float4 h1v = ((const float4*)&g_h1[0][b][0])[k4];
    ((float4*)&g_C0[r][0])[k4] = ((const float4*)&g_c0[b][0])[k4];
    ((float4*)&g_C1[r][0])[k4] = ((const float4*)&g_c1[b][0])[k4];
    const int kb = k4 * 4;
    const float e0[4] = {h0v.x, h0v.y, h0v.z, h0v.w};
    const float e1[4] = {h1v.x, h1v.y, h1v.z, h1v.w};
#pragma unroll
    for (int j = 0; j < 4; ++j) {
      ushort hh = f2bf(e0[j]);
      H0h[0][r][kb + j] = hh;
      H0l[0][r][kb + j] = f2bf(e0[j] - bf2f(hh));
      hh = f2bf(e1[j]);
      H1h[0][r][kb + j] = hh;
      H1l[0][r][kb + j] = f2bf(e1[j] - bf2f(hh));
    }
    if (gt < RR) g_u[0][gt] = init_input[gt];
  }
}

// ======================= DECODER (split-bf16 MFMA GEMMs; R12-verified) =========
__global__ __launch_bounds__(512, 4) void dec_l0(
    const float* __restrict__ w_ih0, const float* __restrict__ b0,
    const float* __restrict__ b_out, float* __restrict__ out, int d) {
  __shared__ __align__(16) ushort Ah[64][72], Al[64][72];
  __shared__ __align__(16) ushort Bh[128][72], Bl[128][72];
  __shared__ float s_wi[128], s_bi[128];
  const int tid = threadIdx.x;
  const int CG = blockIdx.x & 15, RQ = blockIdx.x >> 4;
  const int row0 = RQ * 64, hcol0 = CG * 32;
  const int lane = tid & 63, wv = tid >> 6;
  const int wm = wv & 3, wn = wv >> 2;
  const int mr = lane & 15, kg = lane >> 4;

  if (tid < 128) {
    const int jsrc = (tid >> 5) * HH + hcol0 + (tid & 31);
    s_wi[tid] = w_ih0[jsrc];
    s_bi[tid] = b0[jsrc];
  }

  const int cur = d & 1, nxt = cur ^ 1;
  const ushort* __restrict__ Ahg = &H0h[cur][0][0];
  const ushort* __restrict__ Alg = &H0l[cur][0][0];

  f32x4 acc[4];
#pragma unroll
  for (int g = 0; g < 4; ++g) acc[g] = (f32x4){0.f, 0.f, 0.f, 0.f};

  for (int kt = 0; kt < 8; ++kt) {
    const int k0 = kt * 64;
    __syncthreads();
    {
      const int m = tid >> 3, kk = (tid & 7) * 8;
      *(ushort8*)&Ah[m][kk] = *(const ushort8*)&Ahg[(row0 + m) * HH + k0 + kk];
      *(ushort8*)&Al[m][kk] = *(const ushort8*)&Alg[(row0 + m) * HH + k0 + kk];
    }
#pragma unroll
    for (int i = 0; i < 2; ++i) {
      const int q = i * 512 + tid;
      const int j2 = q >> 3, kk = (q & 7) * 8;
      const int jsrc = (j2 >> 5) * HH + hcol0 + (j2 & 31);
      *(ushort8*)&Bh[j2][kk] = *(const ushort8*)&Whh0h[jsrc][k0 + kk];
      *(ushort8*)&Bl[j2][kk] = *(const ushort8*)&Whh0l[jsrc][k0 + kk];
    }
    __syncthreads();
#pragma unroll
    for (int ks2 = 0; ks2 < 2; ++ks2) {
      const int ko = ks2 * 32 + kg * 8;
      const bf16x8 ah = *(const bf16x8*)&Ah[wm * 16 + mr][ko];
      const bf16x8 al = *(const bf16x8*)&Al[wm * 16 + mr][ko];
#pragma unroll
      for (int g = 0; g < 4; ++g) {
        const bf16x8 bh = *(const bf16x8*)&Bh[g * 32 + wn * 16 + mr][ko];
        const bf16x8 bl = *(const bf16x8*)&Bl[g * 32 + wn * 16 + mr][ko];
        acc[g] = __builtin_amdgcn_mfma_f32_16x16x32_bf16(ah, bh, acc[g], 0, 0, 0);
        acc[g] = __builtin_amdgcn_mfma_f32_16x16x32_bf16(ah, bl, acc[g], 0, 0, 0);
        acc[g] = __builtin_amdgcn_mfma_f32_16x16x32_bf16(al, bh, acc[g], 0, 0, 0);
      }
    }
  }

  const int hl2 = wn * 16 + mr;
  const int hcol = hcol0 + hl2;
  const int ub = d & 1, nb = ub ^ 1;
  const float bo = b_out[0];
#pragma unroll
  for (int r = 0; r < 4; ++r) {
    const int row = row0 + wm * 16 + kg * 4 + r;
    const float u = g_u[ub][row];
    const float iv = acc[0][r] + u * s_wi[hl2] + s_bi[hl2];
    const float fv = acc[1][r] + u * s_wi[32 + hl2] + s_bi[32 + hl2];
    const float gv = acc[2][r] + u * s_wi[64 + hl2] + s_bi[64 + hl2];
    const float ov = acc[3][r] + u * s_wi[96 + hl2] + s_bi[96 + hl2];
    float c = g_C0[row][hcol];
    const float h = cellupd(iv, fv, gv, ov, c);
    g_C0[row][hcol] = c;
    const ushort hh = f2bf(h);
    H0h[nxt][row][hcol] = hh;
    H0l[nxt][row][hcol] = f2bf(h - bf2f(hh));
    if (CG == 0 && wn == 0 && mr == 0) {
      g_u[nb][row] = bo;
      out[row * HOR + d] = bo;
    }
  }
}

__global__ __launch_bounds__(512, 4) void dec_l1(
    const float* __restrict__ b1, const float* __restrict__ w_out,
    float* __restrict__ out, int d) {
  __shared__ __align__(16) ushort Ah[64][72], Al[64][72];
  __shared__ __align__(16) ushort Bh[128][72], Bl[128][72];
  __shared__ float s_bi[128];
  const int tid = threadIdx.x;
  const int CG = blockIdx.x & 15, RQ = blockIdx.x >> 4;
  const int row0 = RQ * 64, hcol0 = CG * 32;
  const int lane = tid & 63, wv = tid >> 6;
  const int wm = wv & 3, wn = wv >> 2;
  const int mr = lane & 15, kg = lane >> 4;

  if (tid < 128) {
    const int jsrc = (tid >> 5) * HH + hcol0 + (tid & 31);
    s_bi[tid] = b1[jsrc];
  }

  const int cur = d & 1, nxt = cur ^ 1;

  f32x4 acc[4];
#pragma unroll
  for (int g = 0; g < 4; ++g) acc[g] = (f32x4){0.f, 0.f, 0.f, 0.f};

#pragma unroll
  for (int src = 0; src < 2; ++src) {
    const ushort* __restrict__ Ahg = src ? &H1h[cur][0][0] : &H0h[nxt][0][0];
    const ushort* __restrict__ Alg = src ? &H1l[cur][0][0] : &H0l[nxt][0][0];
    const ushort* __restrict__ Bhg = src ? &Whh1h[0][0] : &Wih1h[0][0];
    const ushort* __restrict__ Blg = src ? &Whh1l[0][0] : &Wih1l[0][0];
    for (int kt = 0; kt < 8; ++kt) {
      const int k0 = kt * 64;
      __syncthreads();
      {
        const int m = tid >> 3, kk = (tid & 7) * 8;
        *(ushort8*)&Ah[m][kk] = *(const ushort8*)&Ahg[(row0 + m) * HH + k0 + kk];
        *(ushort8*)&Al[m][kk] = *(const ushort8*)&Alg[(row0 + m) * HH + k0 + kk];
      }
#pragma unroll
      for (int i = 0; i < 2; ++i) {
        const int q = i * 512 + tid;
        const int j2 = q >> 3, kk = (q & 7) * 8;
        const int jsrc = (j2 >> 5) * HH + hcol0 + (j2 & 31);
        *(ushort8*)&Bh[j2][kk] = *(const ushort8*)&Bhg[jsrc * HH + k0 + kk];
        *(ushort8*)&Bl[j2][kk] = *(const ushort8*)&Blg[jsrc * HH + k0 + kk];
      }
      __syncthreads();
#pragma unroll
      for (int ks2 = 0; ks2 < 2; ++ks2) {
        const int ko = ks2 * 32 + kg * 8;
        const bf16x8 ah = *(const bf16x8*)&Ah[wm * 16 + mr][ko];
        const bf16x8 al = *(const bf16x8*)&Al[wm * 16 + mr][ko];
#pragma unroll
        for (int g = 0; g < 4; ++g) {
          const bf16x8 bh = *(const bf16x8*)&Bh[g * 32 + wn * 16 + mr][ko];
          const bf16x8 bl = *(const bf16x8*)&Bl[g * 32 + wn * 16 + mr][ko];
          acc[g] = __builtin_amdgcn_mfma_f32_16x16x32_bf16(ah, bh, acc[g], 0, 0, 0);
          acc[g] = __builtin_amdgcn_mfma_f32_16x16x32_bf16(ah, bl, acc[g], 0, 0, 0);
          acc[g] = __builtin_amdgcn_mfma_f32_16x16x32_bf16(al, bh, acc[g], 0, 0, 0);
        }
      }
    }
  }

  const int hl2 = wn * 16 + mr;
  const int hcol = hcol0 + hl2;
  const int nb = (d & 1) ^ 1;
  const float wo = w_out[hcol];
  float pp[4];
#pragma unroll
  for (int r = 0; r < 4; ++r) {
    const int row = row0 + wm * 16 + kg * 4 + r;
    const float iv = acc[0][r] + s_bi[hl2];
    const float fv = acc[1][r] + s_bi[32 + hl2];
    const float gv = acc[2][r] + s_bi[64 + hl2];
    const float ov = acc[3][r] + s_bi[96 + hl2];
    float c = g_C1[row][hcol];
    const float h = cellupd(iv, fv, gv, ov, c);
    g_C1[row][hcol] = c;
    const ushort hh = f2bf(h);
    H1h[nxt][row][hcol] = hh;
    H1l[nxt][row][hcol] = f2bf(h - bf2f(hh));
    pp[r] = h * wo;
  }
#pragma unroll
  for (int off = 1; off < 16; off <<= 1) {
#pragma unroll
    for (int r = 0; r < 4; ++r) pp[r] += __shfl_xor(pp[r], off);
  }
  if (mr == 0) {
#pragma unroll
    for (int r = 0; r < 4; ++r) {
      const int row = row0 + wm * 16 + kg * 4 + r;
      atomicAdd(&g_u[nb][row], pp[r]);
      atomicAdd(&out[row * HOR + d], pp[r]);
    }
  }
}

extern "C" void kernel_launch(void* const* d_in, const int* in_sizes, int n_in,
                              void* d_out, int out_size, void* d_ws, size_t ws_size,
                              hipStream_t stream) {
  (void)in_sizes; (void)n_in; (void)out_size; (void)ws_size;
  const float* x = (const float*)d_in[0];
  const float* init_input = (const float*)d_in[1];
  const float* w_ih0 = (const float*)d_in[2];
  const float* w_hh0 = (const float*)d_in[3];
  const float* b0 = (const float*)d_in[4];
  const float* w_ih1 = (const float*)d_in[5];
  const float* w_hh1 = (const float*)d_in[6];
  const float* b1 = (const float*)d_in[7];
  const float* w_out = (const float*)d_in[8];
  const float* b_out = (const float*)d_in[9];
  float* out = (float*)d_out;

  hipMemsetAsync(d_ws, 0, 3 * 4096 * sizeof(unsigned) + 256, stream);
  prep_split<<<2048, 512, 0, stream>>>(w_hh0, w_ih1, w_hh1);
  enc_kernel<<<ENW, ENT, 0, stream>>>(x, init_input, w_ih0, w_hh0, b0,
                                      w_ih1, w_hh1, b1, (unsigned*)d_ws);
  for (int d = 0; d < HOR; ++d) {
    dec_l0<<<256, 512, 0, stream>>>(w_ih0, b0, b_out, out, d);
    dec_l1<<<256, 512, 0, stream>>>(b1, w_out, out, d);
  }
}

// Round 14
// 14055.562 us; speedup vs baseline: 1.5465x; 1.5465x over previous
//
#include <hip/hip_runtime.h>
#include <math.h>

// Problem constants (fixed by setup_inputs)
#define BB  64      // batch
#define TT  512     // seq len
#define HH  512     // hidden
#define RR  1024    // decode rows = B*S
#define HOR 64      // horizon

// encoder geometry
#define EWG 64      // encoder WGs (each owns 8 hcols = 32 gate-rows)
#define ETH 512     // threads (8 waves)

typedef unsigned short ushort;
typedef __attribute__((ext_vector_type(8))) short bf16x8;     // 8 bf16 (4 VGPRs)
typedef __attribute__((ext_vector_type(8))) unsigned short ushort8;
typedef __attribute__((ext_vector_type(4))) float f32x4;

// Persistent state in device globals (re-initialized every launch)
__device__ float g_c0[BB][HH];
__device__ float g_c1[BB][HH];
__device__ float g_C0[RR][HH];
__device__ float g_C1[RR][HH];
__device__ float g_u[2][RR];       // u double-buffer: g_u[d&1] feeds step d
// encoder h state, split-bf16 (hi + lo residual)
__device__ ushort Eh0h[2][BB][HH], Eh0l[2][BB][HH];
__device__ ushort Eh1h[2][BB][HH], Eh1l[2][BB][HH];
// split-bf16 decoder state (hi + lo residual; GEMM A operands)
__device__ ushort H0h[2][RR][HH], H0l[2][RR][HH];
__device__ ushort H1h[2][RR][HH], H1l[2][RR][HH];
// split-bf16 weights (prep kernel, once per launch)
__device__ ushort Whh0h[4 * HH][HH], Whh0l[4 * HH][HH];
__device__ ushort Wih1h[4 * HH][HH], Wih1l[4 * HH][HH];
__device__ ushort Whh1h[4 * HH][HH], Whh1l[4 * HH][HH];

__device__ __forceinline__ float sigf(float v) { return 1.0f / (1.0f + expf(-v)); }

__device__ __forceinline__ float cellupd(float iv, float fv, float gv, float ov, float& c) {
  c = sigf(fv) * c + sigf(iv) * tanhf(gv);
  return sigf(ov) * tanhf(c);
}

// bf16 RNE helpers
__device__ __forceinline__ ushort f2bf(float x) {
  unsigned u = __float_as_uint(x);
  unsigned r = u + 0x7FFFu + ((u >> 16) & 1u);
  return (ushort)(r >> 16);
}
__device__ __forceinline__ float bf2f(ushort h) {
  return __uint_as_float(((unsigned)h) << 16);
}

// ---- Fence-hoisted barrier, 64 WGs (R11-verified semantics) ----
// Arrival: wbl2 fence + relaxed store to own cacheline. Wait: 64 lanes poll
// the 64 slots directly, then one inv fence. SAFETY (R2/R4 hangs): ~53KB LDS
// -> 2 WG/CU; 64 WGs vs 512 slots = 8x co-residency slack.
__device__ __forceinline__ void ebar_arrive(unsigned* slots, unsigned p) {
  __syncthreads();  // all waves' global writes issued before fence
  if (threadIdx.x == 0) {
    __threadfence();  // wbl2: publish this WG's writes
    __hip_atomic_store(slots + blockIdx.x * 32, p, __ATOMIC_RELAXED,
                       __HIP_MEMORY_SCOPE_AGENT);
  }
}
__device__ __forceinline__ void ebar_wait(unsigned* slots, unsigned p) {
  if (threadIdx.x < EWG) {
    while (__hip_atomic_load(slots + threadIdx.x * 32, __ATOMIC_RELAXED,
                             __HIP_MEMORY_SCOPE_AGENT) < p)
      __builtin_amdgcn_s_sleep(1);
  }
  __syncthreads();
  if (threadIdx.x == 0) __threadfence();  // inv: fresh reads of peers' state
  __syncthreads();
}

// ======================= PREP: split weights to bf16 hi/lo =======================
__global__ __launch_bounds__(512) void prep_split(
    const float* __restrict__ whh0, const float* __restrict__ wih1,
    const float* __restrict__ whh1) {
  const int i = blockIdx.x * 512 + threadIdx.x;  // grid 2048 -> 1M elements
  float a = whh0[i];
  ushort h = f2bf(a);
  (&Whh0h[0][0])[i] = h;
  (&Whh0l[0][0])[i] = f2bf(a - bf2f(h));
  a = wih1[i];
  h = f2bf(a);
  (&Wih1h[0][0])[i] = h;
  (&Wih1l[0][0])[i] = f2bf(a - bf2f(h));
  a = whh1[i];
  h = f2bf(a);
  (&Whh1h[0][0])[i] = h;
  (&Whh1l[0][0])[i] = f2bf(a - bf2f(h));
}

// ======================= ENCODER (persistent, split-bf16 MFMA) =================
// 64 WGs x 512 thr (8 waves). WG owns hcols hcol0..hcol0+7 -> 32 gate-rows
// per matrix (jl = gate*8 + hl). Per tick:
//   pass1/2 (shared A = h0[cur]): acc0 += A@Whh0^T, acc1 += A@Wih1^T
//   pass3:   acc1 += h1[nxt] @ Whh1^T
// each pass 8 k-steps of 64; split-bf16 3-term MFMA (decoder-verified
// fragment pattern: A/B [row][k] LDS; C row=kg*4+r, col=mr).
// Waves: mh=wv&3 -> m-tile (16 batch rows), g2=wv>>2 -> n-tile (16 gate-rows).
// Cell update via LDS gate exchange; h written as bf16 hi/lo.
__global__ __launch_bounds__(ETH, 4) void enc_kernel(
    const float* __restrict__ x, const float* __restrict__ init_input,
    const float* __restrict__ w_ih0, const float* __restrict__ b0,
    const float* __restrict__ b1, unsigned* ws) {
  const int wg = blockIdx.x;
  const int tid = threadIdx.x;
  const int hcol0 = wg * 8;
  unsigned* wsE = ws;           // 64 slots x 32 stride
  unsigned* wsI = ws + 2048;

  __shared__ __align__(16) ushort Ah[64][72], Al[64][72];
  __shared__ __align__(16) ushort B1h[32][72], B1l[32][72];
  __shared__ __align__(16) ushort B2h[32][72], B2l[32][72];
  __shared__ float s_gb0[64 * 32];  // [b][hl][gate]
  __shared__ float s_gb1[64 * 32];
  __shared__ float s_wih0[32], s_b0[32], s_b1[32];

  if (tid < 32) {  // jl = gate*8 + hl
    const int jsrc = (tid >> 3) * HH + hcol0 + (tid & 7);
    s_wih0[tid] = w_ih0[jsrc];
    s_b0[tid] = b0[jsrc];
    s_b1[tid] = b1[jsrc];
  }
  {  // zero-init encoder state (both parities of h; c)
    const int gid = wg * ETH + tid;  // 0..32767 == BB*HH
#pragma unroll
    for (int pb = 0; pb < 2; ++pb) {
      (&Eh0h[pb][0][0])[gid] = 0;
      (&Eh0l[pb][0][0])[gid] = 0;
      (&Eh1h[pb][0][0])[gid] = 0;
      (&Eh1l[pb][0][0])[gid] = 0;
    }
    (&g_c0[0][0])[gid] = 0.f;
    (&g_c1[0][0])[gid] = 0.f;
  }
  ebar_arrive(wsI, 1);
  ebar_wait(wsI, 1);

  const int lane = tid & 63, wv = tid >> 6;
  const int mh = wv & 3;        // m-tile: batch rows mh*16..+15
  const int g2 = wv >> 2;       // n-tile: gate-rows g2*16..+15
  const int mr = lane & 15, kg = lane >> 4;
  // staging indices
  const int sm = tid >> 3, skk = (tid & 7) * 8;       // A: 64 rows x 64 k
  const int bj = (tid & 255) >> 3;                    // B: 32 rows x 64 k
  const int bjsrc = (bj >> 3) * HH + hcol0 + (bj & 7);
  // cell indices
  const int cb = tid >> 3, chl = tid & 7;
  const int chcol = hcol0 + chl;

  unsigned p = 1;
  for (int tk = 1; tk <= TT + 1; ++tk) {
    const int cur = (tk - 1) & 1, nxt = tk & 1;
    const bool do0 = (tk <= TT), do1 = (tk >= 2);

    f32x4 acc0 = {0.f, 0.f, 0.f, 0.f};
    f32x4 acc1 = {0.f, 0.f, 0.f, 0.f};

    // ---- pass 1&2: A = h0[cur]; B1 = Whh0 (->acc0), B2 = Wih1 (->acc1) ----
    const ushort* __restrict__ A0h = &Eh0h[cur][0][0];
    const ushort* __restrict__ A0l = &Eh0l[cur][0][0];
    for (int kt = 0; kt < 8; ++kt) {
      const int k0 = kt * 64;
      __syncthreads();
      *(ushort8*)&Ah[sm][skk] = *(const ushort8*)&A0h[sm * HH + k0 + skk];
      *(ushort8*)&Al[sm][skk] = *(const ushort8*)&A0l[sm * HH + k0 + skk];
      if (tid < 256) {
        *(ushort8*)&B1h[bj][skk] = *(const ushort8*)&Whh0h[bjsrc][k0 + skk];
        *(ushort8*)&B2h[bj][skk] = *(const ushort8*)&Wih1h[bjsrc][k0 + skk];
      } else {
        *(ushort8*)&B1l[bj][skk] = *(const ushort8*)&Whh0l[bjsrc][k0 + skk];
        *(ushort8*)&B2l[bj][skk] = *(const ushort8*)&Wih1l[bjsrc][k0 + skk];
      }
      __syncthreads();
#pragma unroll
      for (int ks2 = 0; ks2 < 2; ++ks2) {
        const int ko = ks2 * 32 + kg * 8;
        const bf16x8 ah = *(const bf16x8*)&Ah[mh * 16 + mr][ko];
        const bf16x8 al = *(const bf16x8*)&Al[mh * 16 + mr][ko];
        if (do0) {
          const bf16x8 bh = *(const bf16x8*)&B1h[g2 * 16 + mr][ko];
          const bf16x8 bl = *(const bf16x8*)&B1l[g2 * 16 + mr][ko];
          acc0 = __builtin_amdgcn_mfma_f32_16x16x32_bf16(ah, bh, acc0, 0, 0, 0);
          acc0 = __builtin_amdgcn_mfma_f32_16x16x32_bf16(ah, bl, acc0, 0, 0, 0);
          acc0 = __builtin_amdgcn_mfma_f32_16x16x32_bf16(al, bh, acc0, 0, 0, 0);
        }
        if (do1) {
          const bf16x8 bh = *(const bf16x8*)&B2h[g2 * 16 + mr][ko];
          const bf16x8 bl = *(const bf16x8*)&B2l[g2 * 16 + mr][ko];
          acc1 = __builtin_amdgcn_mfma_f32_16x16x32_bf16(ah, bh, acc1, 0, 0, 0);
          acc1 = __builtin_amdgcn_mfma_f32_16x16x32_bf16(ah, bl, acc1, 0, 0, 0);
          acc1 = __builtin_amdgcn_mfma_f32_16x16x32_bf16(al, bh, acc1, 0, 0, 0);
        }
      }
    }

    // ---- pass 3: A = h1[nxt] (= h1^{tk-2}); B1 slots = Whh1 (->acc1) ----
    if (do1) {
      const ushort* __restrict__ A1h = &Eh1h[nxt][0][0];
      const ushort* __restrict__ A1l = &Eh1l[nxt][0][0];
      for (int kt = 0; kt < 8; ++kt) {
        const int k0 = kt * 64;
        __syncthreads();
        *(ushort8*)&Ah[sm][skk] = *(const ushort8*)&A1h[sm * HH + k0 + skk];
        *(ushort8*)&Al[sm][skk] = *(const ushort8*)&A1l[sm * HH + k0 + skk];
        if (tid < 256)
          *(ushort8*)&B1h[bj][skk] = *(const ushort8*)&Whh1h[bjsrc][k0 + skk];
        else
          *(ushort8*)&B1l[bj][skk] = *(const ushort8*)&Whh1l[bjsrc][k0 + skk];
        __syncthreads();
#pragma unroll
        for (int ks2 = 0; ks2 < 2; ++ks2) {
          const int ko = ks2 * 32 + kg * 8;
          const bf16x8 ah = *(const bf16x8*)&Ah[mh * 16 + mr][ko];
          const bf16x8 al = *(const bf16x8*)&Al[mh * 16 + mr][ko];
          const bf16x8 bh = *(const bf16x8*)&B1h[g2 * 16 + mr][ko];
          const bf16x8 bl = *(const bf16x8*)&B1l[g2 * 16 + mr][ko];
          acc1 = __builtin_amdgcn_mfma_f32_16x16x32_bf16(ah, bh, acc1, 0, 0, 0);
          acc1 = __builtin_amdgcn_mfma_f32_16x16x32_bf16(ah, bl, acc1, 0, 0, 0);
          acc1 = __builtin_amdgcn_mfma_f32_16x16x32_bf16(al, bh, acc1, 0, 0, 0);
        }
      }
    }

    // ---- gate exchange: C row = mh*16 + kg*4 + r (batch), col jl = g2*16+mr ----
    __syncthreads();
    {
      const int jl = g2 * 16 + mr;
      const int slot = (jl & 7) * 4 + (jl >> 3);  // [hl][gate]
#pragma unroll
      for (int r = 0; r < 4; ++r) {
        const int b = mh * 16 + kg * 4 + r;
        if (do0) s_gb0[b * 32 + slot] = acc0[r];
        if (do1) s_gb1[b * 32 + slot] = acc1[r];
      }
    }
    __syncthreads();

    // ---- cell updates: thread -> (b = tid>>3, hl = tid&7) ----
    if (do0) {  // cell0 -> h0^{tk}
      const float xv = x[cb * TT + (tk - 1)];
      const float4 gb = *(const float4*)&s_gb0[cb * 32 + chl * 4];
      const float iv = gb.x + xv * s_wih0[chl] + s_b0[chl];
      const float fv = gb.y + xv * s_wih0[8 + chl] + s_b0[8 + chl];
      const float gv = gb.z + xv * s_wih0[16 + chl] + s_b0[16 + chl];
      const float ov = gb.w + xv * s_wih0[24 + chl] + s_b0[24 + chl];
      float c = g_c0[cb][chcol];
      const float h = cellupd(iv, fv, gv, ov, c);
      g_c0[cb][chcol] = c;
      const ushort hh = f2bf(h);
      Eh0h[nxt][cb][chcol] = hh;
      Eh0l[nxt][cb][chcol] = f2bf(h - bf2f(hh));
    }
    if (do1) {  // cell1 -> h1^{tk-1}
      const float4 gb = *(const float4*)&s_gb1[cb * 32 + chl * 4];
      const float iv = gb.x + s_b1[chl];
      const float fv = gb.y + s_b1[8 + chl];
      const float gv = gb.z + s_b1[16 + chl];
      const float ov = gb.w + s_b1[24 + chl];
      float c = g_c1[cb][chcol];
      const float h = cellupd(iv, fv, gv, ov, c);
      g_c1[cb][chcol] = c;
      const ushort hh = f2bf(h);
      Eh1h[cur][cb][chcol] = hh;
      Eh1l[cur][cb][chcol] = f2bf(h - bf2f(hh));
    }
    ebar_arrive(wsE, ++p);
    ebar_wait(wsE, p);
  }

  // ---- expand final states over n_samples: row r = b*16+s ----
  // h0^{512} in Eh0[0]; h1^{512} in Eh1[0] (written at tk=513, cur=0).
  {
#pragma unroll
    for (int it = 0; it < 2; ++it) {  // ushort8 slots: RR*HH/8 = 65536
      const int idx = it * 32768 + wg * ETH + tid;
      const int r = idx >> 6, k8 = (idx & 63) * 8, b = r >> 4;
      *(ushort8*)&H0h[0][r][k8] = *(const ushort8*)&Eh0h[0][b][k8];
      *(ushort8*)&H0l[0][r][k8] = *(const ushort8*)&Eh0l[0][b][k8];
      *(ushort8*)&H1h[0][r][k8] = *(const ushort8*)&Eh1h[0][b][k8];
      *(ushort8*)&H1l[0][r][k8] = *(const ushort8*)&Eh1l[0][b][k8];
    }
#pragma unroll
    for (int it = 0; it < 4; ++it) {  // float4 slots: RR*HH/4 = 131072
      const int idx = it * 32768 + wg * ETH + tid;
      const int r = idx >> 7, k4 = (idx & 127) * 4, b = r >> 4;
      *(float4*)&g_C0[r][k4] = *(const float4*)&g_c0[b][k4];
      *(float4*)&g_C1[r][k4] = *(const float4*)&g_c1[b][k4];
    }
    const int gid = wg * ETH + tid;
    if (gid < RR) g_u[0][gid] = init_input[gid];
  }
}

// ======================= DECODER (split-bf16 MFMA GEMMs; R12-verified) =========
__global__ __launch_bounds__(512, 4) void dec_l0(
    const float* __restrict__ w_ih0, const float* __restrict__ b0,
    const float* __restrict__ b_out, float* __restrict__ out, int d) {
  __shared__ __align__(16) ushort Ah[64][72], Al[64][72];
  __shared__ __align__(16) ushort Bh[128][72], Bl[128][72];
  __shared__ float s_wi[128], s_bi[128];
  const int tid = threadIdx.x;
  const int CG = blockIdx.x & 15, RQ = blockIdx.x >> 4;
  const int row0 = RQ * 64, hcol0 = CG * 32;
  const int lane = tid & 63, wv = tid >> 6;
  const int wm = wv & 3, wn = wv >> 2;
  const int mr = lane & 15, kg = lane >> 4;

  if (tid < 128) {
    const int jsrc = (tid >> 5) * HH + hcol0 + (tid & 31);
    s_wi[tid] = w_ih0[jsrc];
    s_bi[tid] = b0[jsrc];
  }

  const int cur = d & 1, nxt = cur ^ 1;
  const ushort* __restrict__ Ahg = &H0h[cur][0][0];
  const ushort* __restrict__ Alg = &H0l[cur][0][0];

  f32x4 acc[4];
#pragma unroll
  for (int g = 0; g < 4; ++g) acc[g] = (f32x4){0.f, 0.f, 0.f, 0.f};

  for (int kt = 0; kt < 8; ++kt) {
    const int k0 = kt * 64;
    __syncthreads();
    {
      const int m = tid >> 3, kk = (tid & 7) * 8;
      *(ushort8*)&Ah[m][kk] = *(const ushort8*)&Ahg[(row0 + m) * HH + k0 + kk];
      *(ushort8*)&Al[m][kk] = *(const ushort8*)&Alg[(row0 + m) * HH + k0 + kk];
    }
#pragma unroll
    for (int i = 0; i < 2; ++i) {
      const int q = i * 512 + tid;
      const int j2 = q >> 3, kk = (q & 7) * 8;
      const int jsrc = (j2 >> 5) * HH + hcol0 + (j2 & 31);
      *(ushort8*)&Bh[j2][kk] = *(const ushort8*)&Whh0h[jsrc][k0 + kk];
      *(ushort8*)&Bl[j2][kk] = *(const ushort8*)&Whh0l[jsrc][k0 + kk];
    }
    __syncthreads();
#pragma unroll
    for (int ks2 = 0; ks2 < 2; ++ks2) {
      const int ko = ks2 * 32 + kg * 8;
      const bf16x8 ah = *(const bf16x8*)&Ah[wm * 16 + mr][ko];
      const bf16x8 al = *(const bf16x8*)&Al[wm * 16 + mr][ko];
#pragma unroll
      for (int g = 0; g < 4; ++g) {
        const bf16x8 bh = *(const bf16x8*)&Bh[g * 32 + wn * 16 + mr][ko];
        const bf16x8 bl = *(const bf16x8*)&Bl[g * 32 + wn * 16 + mr][ko];
        acc[g] = __builtin_amdgcn_mfma_f32_16x16x32_bf16(ah, bh, acc[g], 0, 0, 0);
        acc[g] = __builtin_amdgcn_mfma_f32_16x16x32_bf16(ah, bl, acc[g], 0, 0, 0);
        acc[g] = __builtin_amdgcn_mfma_f32_16x16x32_bf16(al, bh, acc[g], 0, 0, 0);
      }
    }
  }

  const int hl2 = wn * 16 + mr;
  const int hcol = hcol0 + hl2;
  const int ub = d & 1, nb = ub ^ 1;
  const float bo = b_out[0];
#pragma unroll
  for (int r = 0; r < 4; ++r) {
    const int row = row0 + wm * 16 + kg * 4 + r;
    const float u = g_u[ub][row];
    const float iv = acc[0][r] + u * s_wi[hl2] + s_bi[hl2];
    const float fv = acc[1][r] + u * s_wi[32 + hl2] + s_bi[32 + hl2];
    const float gv = acc[2][r] + u * s_wi[64 + hl2] + s_bi[64 + hl2];
    const float ov = acc[3][r] + u * s_wi[96 + hl2] + s_bi[96 + hl2];
    float c = g_C0[row][hcol];
    const float h = cellupd(iv, fv, gv, ov, c);
    g_C0[row][hcol] = c;
    const ushort hh = f2bf(h);
    H0h[nxt][row][hcol] = hh;
    H0l[nxt][row][hcol] = f2bf(h - bf2f(hh));
    if (CG == 0 && wn == 0 && mr == 0) {
      g_u[nb][row] = bo;
      out[row * HOR + d] = bo;
    }
  }
}

__global__ __launch_bounds__(512, 4) void dec_l1(
    const float* __restrict__ b1, const float* __restrict__ w_out,
    float* __restrict__ out, int d) {
  __shared__ __align__(16) ushort Ah[64][72], Al[64][72];
  __shared__ __align__(16) ushort Bh[128][72], Bl[128][72];
  __shared__ float s_bi[128];
  const int tid = threadIdx.x;
  const int CG = blockIdx.x & 15, RQ = blockIdx.x >> 4;
  const int row0 = RQ * 64, hcol0 = CG * 32;
  const int lane = tid & 63, wv = tid >> 6;
  const int wm = wv & 3, wn = wv >> 2;
  const int mr = lane & 15, kg = lane >> 4;

  if (tid < 128) {
    const int jsrc = (tid >> 5) * HH + hcol0 + (tid & 31);
    s_bi[tid] = b1[jsrc];
  }

  const int cur = d & 1, nxt = cur ^ 1;

  f32x4 acc[4];
#pragma unroll
  for (int g = 0; g < 4; ++g) acc[g] = (f32x4){0.f, 0.f, 0.f, 0.f};

#pragma unroll
  for (int src = 0; src < 2; ++src) {
    const ushort* __restrict__ Ahg = src ? &H1h[cur][0][0] : &H0h[nxt][0][0];
    const ushort* __restrict__ Alg = src ? &H1l[cur][0][0] : &H0l[nxt][0][0];
    const ushort* __restrict__ Bhg = src ? &Whh1h[0][0] : &Wih1h[0][0];
    const ushort* __restrict__ Blg = src ? &Whh1l[0][0] : &Wih1l[0][0];
    for (int kt = 0; kt < 8; ++kt) {
      const int k0 = kt * 64;
      __syncthreads();
      {
        const int m = tid >> 3, kk = (tid & 7) * 8;
        *(ushort8*)&Ah[m][kk] = *(const ushort8*)&Ahg[(row0 + m) * HH + k0 + kk];
        *(ushort8*)&Al[m][kk] = *(const ushort8*)&Alg[(row0 + m) * HH + k0 + kk];
      }
#pragma unroll
      for (int i = 0; i < 2; ++i) {
        const int q = i * 512 + tid;
        const int j2 = q >> 3, kk = (q & 7) * 8;
        const int jsrc = (j2 >> 5) * HH + hcol0 + (j2 & 31);
        *(ushort8*)&Bh[j2][kk] = *(const ushort8*)&Bhg[jsrc * HH + k0 + kk];
        *(ushort8*)&Bl[j2][kk] = *(const ushort8*)&Blg[jsrc * HH + k0 + kk];
      }
      __syncthreads();
#pragma unroll
      for (int ks2 = 0; ks2 < 2; ++ks2) {
        const int ko = ks2 * 32 + kg * 8;
        const bf16x8 ah = *(const bf16x8*)&Ah[wm * 16 + mr][ko];
        const bf16x8 al = *(const bf16x8*)&Al[wm * 16 + mr][ko];
#pragma unroll
        for (int g = 0; g < 4; ++g) {
          const bf16x8 bh = *(const bf16x8*)&Bh[g * 32 + wn * 16 + mr][ko];
          const bf16x8 bl = *(const bf16x8*)&Bl[g * 32 + wn * 16 + mr][ko];
          acc[g] = __builtin_amdgcn_mfma_f32_16x16x32_bf16(ah, bh, acc[g], 0, 0, 0);
          acc[g] = __builtin_amdgcn_mfma_f32_16x16x32_bf16(ah, bl, acc[g], 0, 0, 0);
          acc[g] = __builtin_amdgcn_mfma_f32_16x16x32_bf16(al, bh, acc[g], 0, 0, 0);
        }
      }
    }
  }

  const int hl2 = wn * 16 + mr;
  const int hcol = hcol0 + hl2;
  const int nb = (d & 1) ^ 1;
  const float wo = w_out[hcol];
  float pp[4];
#pragma unroll
  for (int r = 0; r < 4; ++r) {
    const int row = row0 + wm * 16 + kg * 4 + r;
    const float iv = acc[0][r] + s_bi[hl2];
    const float fv = acc[1][r] + s_bi[32 + hl2];
    const float gv = acc[2][r] + s_bi[64 + hl2];
    const float ov = acc[3][r] + s_bi[96 + hl2];
    float c = g_C1[row][hcol];
    const float h = cellupd(iv, fv, gv, ov, c);
    g_C1[row][hcol] = c;
    const ushort hh = f2bf(h);
    H1h[nxt][row][hcol] = hh;
    H1l[nxt][row][hcol] = f2bf(h - bf2f(hh));
    pp[r] = h * wo;
  }
#pragma unroll
  for (int off = 1; off < 16; off <<= 1) {
#pragma unroll
    for (int r = 0; r < 4; ++r) pp[r] += __shfl_xor(pp[r], off);
  }
  if (mr == 0) {
#pragma unroll
    for (int r = 0; r < 4; ++r) {
      const int row = row0 + wm * 16 + kg * 4 + r;
      atomicAdd(&g_u[nb][row], pp[r]);
      atomicAdd(&out[row * HOR + d], pp[r]);
    }
  }
}

extern "C" void kernel_launch(void* const* d_in, const int* in_sizes, int n_in,
                              void* d_out, int out_size, void* d_ws, size_t ws_size,
                              hipStream_t stream) {
  (void)in_sizes; (void)n_in; (void)out_size; (void)ws_size;
  const float* x = (const float*)d_in[0];
  const float* init_input = (const float*)d_in[1];
  const float* w_ih0 = (const float*)d_in[2];
  const float* w_hh0 = (const float*)d_in[3];
  const float* b0 = (const float*)d_in[4];
  const float* w_ih1 = (const float*)d_in[5];
  const float* w_hh1 = (const float*)d_in[6];
  const float* b1 = (const float*)d_in[7];
  const float* w_out = (const float*)d_in[8];
  const float* b_out = (const float*)d_in[9];
  float* out = (float*)d_out;

  hipMemsetAsync(d_ws, 0, 4096 * sizeof(unsigned), stream);
  prep_split<<<2048, 512, 0, stream>>>(w_hh0, w_ih1, w_hh1);
  enc_kernel<<<EWG, ETH, 0, stream>>>(x, init_input, w_ih0, b0, b1,
                                      (unsigned*)d_ws);
  for (int d = 0; d < HOR; ++d) {
    dec_l0<<<256, 512, 0, stream>>>(w_ih0, b0, b_out, out, d);
    dec_l1<<<256, 512, 0, stream>>>(b1, w_out, out, d);
  }
}

// Round 15
// 13176.140 us; speedup vs baseline: 1.6497x; 1.0667x over previous
//
#include <hip/hip_runtime.h>
#include <math.h>

// Problem constants (fixed by setup_inputs)
#define BB  64      // batch
#define TT  512     // seq len
#define HH  512     // hidden
#define RR  1024    // decode rows = B*S
#define HOR 64      // horizon

// encoder geometry
#define EWG 128     // encoder WGs (each owns 4 hcols = 16 gate-rows/matrix)
#define ETH 512     // threads (8 waves)

typedef unsigned short ushort;
typedef __attribute__((ext_vector_type(8))) short bf16x8;     // 8 bf16 (4 VGPRs)
typedef __attribute__((ext_vector_type(8))) unsigned short ushort8;
typedef __attribute__((ext_vector_type(4))) float f32x4;

// Persistent state in device globals (re-initialized every launch)
__device__ float g_c0[BB][HH];
__device__ float g_c1[BB][HH];
__device__ float g_C0[RR][HH];
__device__ float g_C1[RR][HH];
__device__ float g_u[2][RR];       // u double-buffer: g_u[d&1] feeds step d
// encoder h state, split-bf16 (hi + lo residual)
__device__ ushort Eh0h[2][BB][HH], Eh0l[2][BB][HH];
__device__ ushort Eh1h[2][BB][HH], Eh1l[2][BB][HH];
// split-bf16 decoder state (hi + lo residual; GEMM A operands)
__device__ ushort H0h[2][RR][HH], H0l[2][RR][HH];
__device__ ushort H1h[2][RR][HH], H1l[2][RR][HH];
// split-bf16 weights (prep kernel, once per launch)
__device__ ushort Whh0h[4 * HH][HH], Whh0l[4 * HH][HH];
__device__ ushort Wih1h[4 * HH][HH], Wih1l[4 * HH][HH];
__device__ ushort Whh1h[4 * HH][HH], Whh1l[4 * HH][HH];

__device__ __forceinline__ float sigf(float v) { return 1.0f / (1.0f + expf(-v)); }

__device__ __forceinline__ float cellupd(float iv, float fv, float gv, float ov, float& c) {
  c = sigf(fv) * c + sigf(iv) * tanhf(gv);
  return sigf(ov) * tanhf(c);
}

// bf16 RNE helpers
__device__ __forceinline__ ushort f2bf(float x) {
  unsigned u = __float_as_uint(x);
  unsigned r = u + 0x7FFFu + ((u >> 16) & 1u);
  return (ushort)(r >> 16);
}
__device__ __forceinline__ float bf2f(ushort h) {
  return __uint_as_float(((unsigned)h) << 16);
}

// ---- Fence-hoisted barrier, 128 WGs (R11-verified semantics) ----
// Arrival: wbl2 fence + relaxed store to own cacheline. Wait: 128 lanes poll
// the slots directly, then one inv fence. SAFETY (R2/R4 hangs): ~108KB LDS
// -> 1 WG/CU; 128 WGs vs 256 CUs = 2x co-residency slack. Keep it so.
__device__ __forceinline__ void ebar_arrive(unsigned* slots, unsigned p) {
  __syncthreads();
  if (threadIdx.x == 0) {
    __threadfence();  // wbl2: publish this WG's writes
    __hip_atomic_store(slots + blockIdx.x * 32, p, __ATOMIC_RELAXED,
                       __HIP_MEMORY_SCOPE_AGENT);
  }
}
__device__ __forceinline__ void ebar_wait(unsigned* slots, unsigned p) {
  if (threadIdx.x < EWG) {
    while (__hip_atomic_load(slots + threadIdx.x * 32, __ATOMIC_RELAXED,
                             __HIP_MEMORY_SCOPE_AGENT) < p)
      __builtin_amdgcn_s_sleep(1);
  }
  __syncthreads();
  if (threadIdx.x == 0) __threadfence();  // inv: fresh reads of peers' state
  __syncthreads();
}

// ======================= PREP: split weights to bf16 hi/lo =======================
__global__ __launch_bounds__(512) void prep_split(
    const float* __restrict__ whh0, const float* __restrict__ wih1,
    const float* __restrict__ whh1) {
  const int i = blockIdx.x * 512 + threadIdx.x;  // grid 2048 -> 1M elements
  float a = whh0[i];
  ushort h = f2bf(a);
  (&Whh0h[0][0])[i] = h;
  (&Whh0l[0][0])[i] = f2bf(a - bf2f(h));
  a = wih1[i];
  h = f2bf(a);
  (&Wih1h[0][0])[i] = h;
  (&Wih1l[0][0])[i] = f2bf(a - bf2f(h));
  a = whh1[i];
  h = f2bf(a);
  (&Whh1h[0][0])[i] = h;
  (&Whh1l[0][0])[i] = f2bf(a - bf2f(h));
}

// swizzled ushort offset within a 16x512 weight plane for (row jl, chunk ck)
__device__ __forceinline__ int wswz(int jl, int ck) {
  return jl * 512 + (((ck & 56) | ((ck ^ jl) & 7)) << 3);
}

// ======================= ENCODER (persistent, split-bf16 MFMA) =================
// 128 WGs x 512 thr (8 waves). WG owns hcols hcol0..+3 -> 16 gate-rows per
// matrix (jl = gate*4 + hl). Weights LDS-RESIDENT (loaded once, XOR-swizzled
// ushort8 chunks; ~2-way banks). A-fragments read DIRECTLY global->VGPR
// (h state is L2-resident). Wave split: waves 0-3 (grp 0): gates0 = h0@Whh0
// (full k) + h0@Wih1 (kt 0-3); waves 4-7 (grp 1): h0@Wih1 (kt 4-7) +
// h1@Whh1 (full k). gates1 = partialA + partialB, summed at the cell.
// MFMA fragment pattern is the decoder-verified one (A row=mr, C row=kg*4+r,
// C col=mr).
__global__ __launch_bounds__(ETH, 4) void enc_kernel(
    const float* __restrict__ x, const float* __restrict__ init_input,
    const float* __restrict__ w_ih0, const float* __restrict__ b0,
    const float* __restrict__ b1, unsigned* ws) {
  const int wg = blockIdx.x;
  const int tid = threadIdx.x;
  const int hcol0 = wg * 4;
  unsigned* wsE = ws;           // 128 slots x 32 stride
  unsigned* wsI = ws + 4096;

  __shared__ __align__(16) ushort sW[6][16 * 512];  // [mat*2+half]
  __shared__ float s_gb0[64 * 16];   // [b][hl*4+gate]
  __shared__ float s_gb1a[64 * 16];
  __shared__ float s_gb1b[64 * 16];
  __shared__ float s_wih0[16], s_b0[16], s_b1[16];

  // ---- load resident weight slices (once): 6 planes x 1024 chunks ----
  for (int i = tid; i < 6 * 1024; i += ETH) {
    const int plane = i >> 10, c = i & 1023;
    const int row = c >> 6, ck = c & 63;
    const int jsrc = (row >> 2) * HH + hcol0 + (row & 3);
    const ushort* src;
    switch (plane) {
      case 0: src = &Whh0h[0][0]; break;
      case 1: src = &Whh0l[0][0]; break;
      case 2: src = &Wih1h[0][0]; break;
      case 3: src = &Wih1l[0][0]; break;
      case 4: src = &Whh1h[0][0]; break;
      default: src = &Whh1l[0][0]; break;
    }
    *(ushort8*)&sW[plane][wswz(row, ck)] =
        *(const ushort8*)&src[jsrc * HH + ck * 8];
  }
  if (tid < 16) {  // jl = gate*4 + hl
    const int jsrc = (tid >> 2) * HH + hcol0 + (tid & 3);
    s_wih0[tid] = w_ih0[jsrc];
    s_b0[tid] = b0[jsrc];
    s_b1[tid] = b1[jsrc];
  }
  {  // zero-init encoder state (both parities of h; c)
    const int gid = wg * ETH + tid;  // 0..65535; state has 32768 elements
    if (gid < BB * HH) {
#pragma unroll
      for (int pb = 0; pb < 2; ++pb) {
        (&Eh0h[pb][0][0])[gid] = 0;
        (&Eh0l[pb][0][0])[gid] = 0;
        (&Eh1h[pb][0][0])[gid] = 0;
        (&Eh1l[pb][0][0])[gid] = 0;
      }
      (&g_c0[0][0])[gid] = 0.f;
      (&g_c1[0][0])[gid] = 0.f;
    }
  }
  ebar_arrive(wsI, 1);
  ebar_wait(wsI, 1);

  const int lane = tid & 63, wv = tid >> 6;
  const int grp = wv >> 2;      // 0: gates0+Wih1(lo-k); 1: Whh1+Wih1(hi-k)
  const int mh = wv & 3;        // m-tile: batch rows mh*16..+15
  const int mr = lane & 15, kg = lane >> 4;
  const int arow = mh * 16 + mr;
  // cell indices
  const int cb = tid >> 2, chl = tid & 3;
  const int chcol = hcol0 + chl;

  unsigned p = 1;
  for (int tk = 1; tk <= TT + 1; ++tk) {
    const int cur = (tk - 1) & 1, nxt = tk & 1;
    const bool do0 = (tk <= TT), do1 = (tk >= 2);

    f32x4 acc0 = {0.f, 0.f, 0.f, 0.f};
    f32x4 acc1 = {0.f, 0.f, 0.f, 0.f};

    if (grp == 0) {
      for (int kt = 0; kt < 8; ++kt) {
#pragma unroll
        for (int ks2 = 0; ks2 < 2; ++ks2) {
          const int kb = kt * 64 + ks2 * 32 + kg * 8;
          const int ck = kt * 8 + ks2 * 4 + kg;
          const bf16x8 ah = *(const bf16x8*)&Eh0h[cur][arow][kb];
          const bf16x8 al = *(const bf16x8*)&Eh0l[cur][arow][kb];
          if (do0) {
            const bf16x8 bh = *(const bf16x8*)&sW[0][wswz(mr, ck)];
            const bf16x8 bl = *(const bf16x8*)&sW[1][wswz(mr, ck)];
            acc0 = __builtin_amdgcn_mfma_f32_16x16x32_bf16(ah, bh, acc0, 0, 0, 0);
            acc0 = __builtin_amdgcn_mfma_f32_16x16x32_bf16(ah, bl, acc0, 0, 0, 0);
            acc0 = __builtin_amdgcn_mfma_f32_16x16x32_bf16(al, bh, acc0, 0, 0, 0);
          }
          if (do1 && kt < 4) {
            const bf16x8 bh = *(const bf16x8*)&sW[2][wswz(mr, ck)];
            const bf16x8 bl = *(const bf16x8*)&sW[3][wswz(mr, ck)];
            acc1 = __builtin_amdgcn_mfma_f32_16x16x32_bf16(ah, bh, acc1, 0, 0, 0);
            acc1 = __builtin_amdgcn_mfma_f32_16x16x32_bf16(ah, bl, acc1, 0, 0, 0);
            acc1 = __builtin_amdgcn_mfma_f32_16x16x32_bf16(al, bh, acc1, 0, 0, 0);
          }
        }
      }
    } else if (do1) {
      for (int kt = 0; kt < 8; ++kt) {
#pragma unroll
        for (int ks2 = 0; ks2 < 2; ++ks2) {
          const int kb = kt * 64 + ks2 * 32 + kg * 8;
          const int ck = kt * 8 + ks2 * 4 + kg;
          if (kt >= 4) {
            const bf16x8 ah = *(const bf16x8*)&Eh0h[cur][arow][kb];
            const bf16x8 al = *(const bf16x8*)&Eh0l[cur][arow][kb];
            const bf16x8 bh = *(const bf16x8*)&sW[2][wswz(mr, ck)];
            const bf16x8 bl = *(const bf16x8*)&sW[3][wswz(mr, ck)];
            acc1 = __builtin_amdgcn_mfma_f32_16x16x32_bf16(ah, bh, acc1, 0, 0, 0);
            acc1 = __builtin_amdgcn_mfma_f32_16x16x32_bf16(ah, bl, acc1, 0, 0, 0);
            acc1 = __builtin_amdgcn_mfma_f32_16x16x32_bf16(al, bh, acc1, 0, 0, 0);
          }
          const bf16x8 a1h = *(const bf16x8*)&Eh1h[nxt][arow][kb];
          const bf16x8 a1l = *(const bf16x8*)&Eh1l[nxt][arow][kb];
          const bf16x8 bh = *(const bf16x8*)&sW[4][wswz(mr, ck)];
          const bf16x8 bl = *(const bf16x8*)&sW[5][wswz(mr, ck)];
          acc1 = __builtin_amdgcn_mfma_f32_16x16x32_bf16(a1h, bh, acc1, 0, 0, 0);
          acc1 = __builtin_amdgcn_mfma_f32_16x16x32_bf16(a1h, bl, acc1, 0, 0, 0);
          acc1 = __builtin_amdgcn_mfma_f32_16x16x32_bf16(a1l, bh, acc1, 0, 0, 0);
        }
      }
    }

    // ---- gate exchange: C row (batch) = mh*16 + kg*4 + r, col jl = mr ----
    {
      const int slot = (mr & 3) * 4 + (mr >> 2);  // [hl][gate]
#pragma unroll
      for (int r = 0; r < 4; ++r) {
        const int b = mh * 16 + kg * 4 + r;
        if (grp == 0) {
          if (do0) s_gb0[b * 16 + slot] = acc0[r];
          if (do1) s_gb1a[b * 16 + slot] = acc1[r];
        } else if (do1) {
          s_gb1b[b * 16 + slot] = acc1[r];
        }
      }
    }
    __syncthreads();

    // ---- cell updates: thread -> (b = tid>>2, hl = tid&3), tid < 256 ----
    if (tid < 256) {
      if (do0) {  // cell0 -> h0^{tk}
        const float xv = x[cb * TT + (tk - 1)];
        const float4 gb = *(const float4*)&s_gb0[cb * 16 + chl * 4];
        const float iv = gb.x + xv * s_wih0[chl] + s_b0[chl];
        const float fv = gb.y + xv * s_wih0[4 + chl] + s_b0[4 + chl];
        const float gv = gb.z + xv * s_wih0[8 + chl] + s_b0[8 + chl];
        const float ov = gb.w + xv * s_wih0[12 + chl] + s_b0[12 + chl];
        float c = g_c0[cb][chcol];
        const float h = cellupd(iv, fv, gv, ov, c);
        g_c0[cb][chcol] = c;
        const ushort hh = f2bf(h);
        Eh0h[nxt][cb][chcol] = hh;
        Eh0l[nxt][cb][chcol] = f2bf(h - bf2f(hh));
      }
      if (do1) {  // cell1 -> h1^{tk-1}
        const float4 ga = *(const float4*)&s_gb1a[cb * 16 + chl * 4];
        const float4 gbb = *(const float4*)&s_gb1b[cb * 16 + chl * 4];
        const float iv = ga.x + gbb.x + s_b1[chl];
        const float fv = ga.y + gbb.y + s_b1[4 + chl];
        const float gv = ga.z + gbb.z + s_b1[8 + chl];
        const float ov = ga.w + gbb.w + s_b1[12 + chl];
        float c = g_c1[cb][chcol];
        const float h = cellupd(iv, fv, gv, ov, c);
        g_c1[cb][chcol] = c;
        const ushort hh = f2bf(h);
        Eh1h[cur][cb][chcol] = hh;
        Eh1l[cur][cb][chcol] = f2bf(h - bf2f(hh));
      }
    }
    ebar_arrive(wsE, ++p);
    ebar_wait(wsE, p);
  }

  // ---- expand final states over n_samples: row r = b*16+s ----
  {
    {  // ushort8 slots: RR*HH/8 = 65536 == grid threads
      const int idx = wg * ETH + tid;
      const int r = idx >> 6, k8 = (idx & 63) * 8, b = r >> 4;
      *(ushort8*)&H0h[0][r][k8] = *(const ushort8*)&Eh0h[0][b][k8];
      *(ushort8*)&H0l[0][r][k8] = *(const ushort8*)&Eh0l[0][b][k8];
      *(ushort8*)&H1h[0][r][k8] = *(const ushort8*)&Eh1h[0][b][k8];
      *(ushort8*)&H1l[0][r][k8] = *(const ushort8*)&Eh1l[0][b][k8];
    }
#pragma unroll
    for (int it = 0; it < 2; ++it) {  // float4 slots: RR*HH/4 = 131072
      const int idx = it * 65536 + wg * ETH + tid;
      const int r = idx >> 7, k4 = (idx & 127) * 4, b = r >> 4;
      *(float4*)&g_C0[r][k4] = *(const float4*)&g_c0[b][k4];
      *(float4*)&g_C1[r][k4] = *(const float4*)&g_c1[b][k4];
    }
    const int gid = wg * ETH + tid;
    if (gid < RR) g_u[0][gid] = init_input[gid];
  }
}

// ======================= DECODER (split-bf16 MFMA GEMMs; R12-verified) =========
__global__ __launch_bounds__(512, 4) void dec_l0(
    const float* __restrict__ w_ih0, const float* __restrict__ b0,
    const float* __restrict__ b_out, float* __restrict__ out, int d) {
  __shared__ __align__(16) ushort Ah[64][72], Al[64][72];
  __shared__ __align__(16) ushort Bh[128][72], Bl[128][72];
  __shared__ float s_wi[128], s_bi[128];
  const int tid = threadIdx.x;
  const int CG = blockIdx.x & 15, RQ = blockIdx.x >> 4;
  const int row0 = RQ * 64, hcol0 = CG * 32;
  const int lane = tid & 63, wv = tid >> 6;
  const int wm = wv & 3, wn = wv >> 2;
  const int mr = lane & 15, kg = lane >> 4;

  if (tid < 128) {
    const int jsrc = (tid >> 5) * HH + hcol0 + (tid & 31);
    s_wi[tid] = w_ih0[jsrc];
    s_bi[tid] = b0[jsrc];
  }

  const int cur = d & 1, nxt = cur ^ 1;
  const ushort* __restrict__ Ahg = &H0h[cur][0][0];
  const ushort* __restrict__ Alg = &H0l[cur][0][0];

  f32x4 acc[4];
#pragma unroll
  for (int g = 0; g < 4; ++g) acc[g] = (f32x4){0.f, 0.f, 0.f, 0.f};

  for (int kt = 0; kt < 8; ++kt) {
    const int k0 = kt * 64;
    __syncthreads();
    {
      const int m = tid >> 3, kk = (tid & 7) * 8;
      *(ushort8*)&Ah[m][kk] = *(const ushort8*)&Ahg[(row0 + m) * HH + k0 + kk];
      *(ushort8*)&Al[m][kk] = *(const ushort8*)&Alg[(row0 + m) * HH + k0 + kk];
    }
#pragma unroll
    for (int i = 0; i < 2; ++i) {
      const int q = i * 512 + tid;
      const int j2 = q >> 3, kk = (q & 7) * 8;
      const int jsrc = (j2 >> 5) * HH + hcol0 + (j2 & 31);
      *(ushort8*)&Bh[j2][kk] = *(const ushort8*)&Whh0h[jsrc][k0 + kk];
      *(ushort8*)&Bl[j2][kk] = *(const ushort8*)&Whh0l[jsrc][k0 + kk];
    }
    __syncthreads();
#pragma unroll
    for (int ks2 = 0; ks2 < 2; ++ks2) {
      const int ko = ks2 * 32 + kg * 8;
      const bf16x8 ah = *(const bf16x8*)&Ah[wm * 16 + mr][ko];
      const bf16x8 al = *(const bf16x8*)&Al[wm * 16 + mr][ko];
#pragma unroll
      for (int g = 0; g < 4; ++g) {
        const bf16x8 bh = *(const bf16x8*)&Bh[g * 32 + wn * 16 + mr][ko];
        const bf16x8 bl = *(const bf16x8*)&Bl[g * 32 + wn * 16 + mr][ko];
        acc[g] = __builtin_amdgcn_mfma_f32_16x16x32_bf16(ah, bh, acc[g], 0, 0, 0);
        acc[g] = __builtin_amdgcn_mfma_f32_16x16x32_bf16(ah, bl, acc[g], 0, 0, 0);
        acc[g] = __builtin_amdgcn_mfma_f32_16x16x32_bf16(al, bh, acc[g], 0, 0, 0);
      }
    }
  }

  const int hl2 = wn * 16 + mr;
  const int hcol = hcol0 + hl2;
  const int ub = d & 1, nb = ub ^ 1;
  const float bo = b_out[0];
#pragma unroll
  for (int r = 0; r < 4; ++r) {
    const int row = row0 + wm * 16 + kg * 4 + r;
    const float u = g_u[ub][row];
    const float iv = acc[0][r] + u * s_wi[hl2] + s_bi[hl2];
    const float fv = acc[1][r] + u * s_wi[32 + hl2] + s_bi[32 + hl2];
    const float gv = acc[2][r] + u * s_wi[64 + hl2] + s_bi[64 + hl2];
    const float ov = acc[3][r] + u * s_wi[96 + hl2] + s_bi[96 + hl2];
    float c = g_C0[row][hcol];
    const float h = cellupd(iv, fv, gv, ov, c);
    g_C0[row][hcol] = c;
    const ushort hh = f2bf(h);
    H0h[nxt][row][hcol] = hh;
    H0l[nxt][row][hcol] = f2bf(h - bf2f(hh));
    if (CG == 0 && wn == 0 && mr == 0) {
      g_u[nb][row] = bo;
      out[row * HOR + d] = bo;
    }
  }
}

__global__ __launch_bounds__(512, 4) void dec_l1(
    const float* __restrict__ b1, const float* __restrict__ w_out,
    float* __restrict__ out, int d) {
  __shared__ __align__(16) ushort Ah[64][72], Al[64][72];
  __shared__ __align__(16) ushort Bh[128][72], Bl[128][72];
  __shared__ float s_bi[128];
  const int tid = threadIdx.x;
  const int CG = blockIdx.x & 15, RQ = blockIdx.x >> 4;
  const int row0 = RQ * 64, hcol0 = CG * 32;
  const int lane = tid & 63, wv = tid >> 6;
  const int wm = wv & 3, wn = wv >> 2;
  const int mr = lane & 15, kg = lane >> 4;

  if (tid < 128) {
    const int jsrc = (tid >> 5) * HH + hcol0 + (tid & 31);
    s_bi[tid] = b1[jsrc];
  }

  const int cur = d & 1, nxt = cur ^ 1;

  f32x4 acc[4];
#pragma unroll
  for (int g = 0; g < 4; ++g) acc[g] = (f32x4){0.f, 0.f, 0.f, 0.f};

#pragma unroll
  for (int src = 0; src < 2; ++src) {
    const ushort* __restrict__ Ahg = src ? &H1h[cur][0][0] : &H0h[nxt][0][0];
    const ushort* __restrict__ Alg = src ? &H1l[cur][0][0] : &H0l[nxt][0][0];
    const ushort* __restrict__ Bhg = src ? &Whh1h[0][0] : &Wih1h[0][0];
    const ushort* __restrict__ Blg = src ? &Whh1l[0][0] : &Wih1l[0][0];
    for (int kt = 0; kt < 8; ++kt) {
      const int k0 = kt * 64;
      __syncthreads();
      {
        const int m = tid >> 3, kk = (tid & 7) * 8;
        *(ushort8*)&Ah[m][kk] = *(const ushort8*)&Ahg[(row0 + m) * HH + k0 + kk];
        *(ushort8*)&Al[m][kk] = *(const ushort8*)&Alg[(row0 + m) * HH + k0 + kk];
      }
#pragma unroll
      for (int i = 0; i < 2; ++i) {
        const int q = i * 512 + tid;
        const int j2 = q >> 3, kk = (q & 7) * 8;
        const int jsrc = (j2 >> 5) * HH + hcol0 + (j2 & 31);
        *(ushort8*)&Bh[j2][kk] = *(const ushort8*)&Bhg[jsrc * HH + k0 + kk];
        *(ushort8*)&Bl[j2][kk] = *(const ushort8*)&Blg[jsrc * HH + k0 + kk];
      }
      __syncthreads();
#pragma unroll
      for (int ks2 = 0; ks2 < 2; ++ks2) {
        const int ko = ks2 * 32 + kg * 8;
        const bf16x8 ah = *(const bf16x8*)&Ah[wm * 16 + mr][ko];
        const bf16x8 al = *(const bf16x8*)&Al[wm * 16 + mr][ko];
#pragma unroll
        for (int g = 0; g < 4; ++g) {
          const bf16x8 bh = *(const bf16x8*)&Bh[g * 32 + wn * 16 + mr][ko];
          const bf16x8 bl = *(const bf16x8*)&Bl[g * 32 + wn * 16 + mr][ko];
          acc[g] = __builtin_amdgcn_mfma_f32_16x16x32_bf16(ah, bh, acc[g], 0, 0, 0);
          acc[g] = __builtin_amdgcn_mfma_f32_16x16x32_bf16(ah, bl, acc[g], 0, 0, 0);
          acc[g] = __builtin_amdgcn_mfma_f32_16x16x32_bf16(al, bh, acc[g], 0, 0, 0);
        }
      }
    }
  }

  const int hl2 = wn * 16 + mr;
  const int hcol = hcol0 + hl2;
  const int nb = (d & 1) ^ 1;
  const float wo = w_out[hcol];
  float pp[4];
#pragma unroll
  for (int r = 0; r < 4; ++r) {
    const int row = row0 + wm * 16 + kg * 4 + r;
    const float iv = acc[0][r] + s_bi[hl2];
    const float fv = acc[1][r] + s_bi[32 + hl2];
    const float gv = acc[2][r] + s_bi[64 + hl2];
    const float ov = acc[3][r] + s_bi[96 + hl2];
    float c = g_C1[row][hcol];
    const float h = cellupd(iv, fv, gv, ov, c);
    g_C1[row][hcol] = c;
    const ushort hh = f2bf(h);
    H1h[nxt][row][hcol] = hh;
    H1l[nxt][row][hcol] = f2bf(h - bf2f(hh));
    pp[r] = h * wo;
  }
#pragma unroll
  for (int off = 1; off < 16; off <<= 1) {
#pragma unroll
    for (int r = 0; r < 4; ++r) pp[r] += __shfl_xor(pp[r], off);
  }
  if (mr == 0) {
#pragma unroll
    for (int r = 0; r < 4; ++r) {
      const int row = row0 + wm * 16 + kg * 4 + r;
      atomicAdd(&g_u[nb][row], pp[r]);
      atomicAdd(&out[row * HOR + d], pp[r]);
    }
  }
}

extern "C" void kernel_launch(void* const* d_in, const int* in_sizes, int n_in,
                              void* d_out, int out_size, void* d_ws, size_t ws_size,
                              hipStream_t stream) {
  (void)in_sizes; (void)n_in; (void)out_size; (void)ws_size;
  const float* x = (const float*)d_in[0];
  const float* init_input = (const float*)d_in[1];
  const float* w_ih0 = (const float*)d_in[2];
  const float* w_hh0 = (const float*)d_in[3];
  const float* b0 = (const float*)d_in[4];
  const float* w_ih1 = (const float*)d_in[5];
  const float* w_hh1 = (const float*)d_in[6];
  const float* b1 = (const float*)d_in[7];
  const float* w_out = (const float*)d_in[8];
  const float* b_out = (const float*)d_in[9];
  float* out = (float*)d_out;

  hipMemsetAsync(d_ws, 0, 8192 * sizeof(unsigned), stream);
  prep_split<<<2048, 512, 0, stream>>>(w_hh0, w_ih1, w_hh1);
  enc_kernel<<<EWG, ETH, 0, stream>>>(x, init_input, w_ih0, b0, b1,
                                      (unsigned*)d_ws);
  for (int d = 0; d < HOR; ++d) {
    dec_l0<<<256, 512, 0, stream>>>(w_ih0, b0, b_out, out, d);
    dec_l1<<<256, 512, 0, stream>>>(b1, w_out, out, d);
  }
}